// Round 11
// baseline (1387.567 us; speedup 1.0000x reference)
//
#include <hip/hip_runtime.h>

// 2-layer GRU (TF GRUCell) + dense via bf16 MFMA.
// R11 = R10 structure (NB=16, 4 barriers/step via RH buffers, LGKM-only
// barriers, cross-phase register prefetch) with 16 WAVES per block
// (1024 threads): each wave owns half the R10 column set, so per-CU
// wave-parallelism doubles (2 -> 4 waves/SIMD) at IDENTICAL aggregate
// weight traffic. Layer1: wave w owns r-cols/u-cols/cand-cols [16w,16w+16)
// (u carried in regs). Layer2: waves 0-7 own u2+cand2 cols (u2 in regs),
// waves 8-15 own r2 cols (write r2*h2 to RH2).

typedef unsigned short u16;
typedef __attribute__((ext_vector_type(8))) short bhalf8;   // 8 bf16
typedef __attribute__((ext_vector_type(4))) float fx4;

constexpr int Bc = 4096, Tc = 64, Fc = 32, U1 = 256, U2 = 128;
constexpr int K1 = Fc + U1;   // 288
constexpr int K2 = U1 + U2;   // 384
constexpr int NB = 16, NTHR = 1024;
constexpr int LD1 = 296;      // A1 row stride (u16)
constexpr int LD2 = 392;      // A2 row stride
constexpr int LDR1 = 264;     // RH1 row stride
constexpr int LDR2 = 136;     // RH2 row stride

constexpr int nW1g = K1 * 512, nW1c = K1 * 256, nW2g = K2 * 256, nW2c = K2 * 128;
constexpr int oW1g = 0;
constexpr int oW1c = oW1g + nW1g;
constexpr int oW2g = oW1c + nW1c;
constexpr int oW2c = oW2g + nW2g;
constexpr int WTOT = oW2c + nW2c;   // 368640 u16
constexpr int nWdT = Fc * U2;       // 4096 floats

constexpr int oA1h = 0;
constexpr int oA1l = oA1h + 16 * LD1;
constexpr int oA2h = oA1l + 16 * LD1;
constexpr int oA2l = oA2h + 16 * LD2;
constexpr int oR1h = oA2l + 16 * LD2;
constexpr int oR1l = oR1h + 16 * LDR1;
constexpr int oR2h = oR1l + 16 * LDR1;
constexpr int oR2l = oR2h + 16 * LDR2;
constexpr int SM_TOT = oR2l + 16 * LDR2;          // 34816 u16
constexpr size_t SMEM_BYTES = (size_t)SM_TOT * 2; // 69632 B

#define LGKM_BARRIER() asm volatile("s_waitcnt lgkmcnt(0)\n\ts_barrier" ::: "memory")

__device__ __forceinline__ u16 bf16_rne(float x) {
  unsigned u = __float_as_uint(x);
  return (u16)((u + 0x7fffu + ((u >> 16) & 1u)) >> 16);
}
__device__ __forceinline__ float bf16_f(u16 h) {
  return __uint_as_float(((unsigned)h) << 16);
}
__device__ __forceinline__ float sigm(float x) { return 1.0f / (1.0f + __expf(-x)); }
__device__ __forceinline__ float tanh_(float x) {
  x = fminf(fmaxf(x, -15.0f), 15.0f);
  const float s = __expf(2.0f * x);
  return (s - 1.0f) / (s + 1.0f);
}

// ---- prep: W[K][N] fp32 -> WT[N][K] bf16; Wd[128][32] -> WdT fp32 ----
__global__ void prep_weights(const float* __restrict__ W1g, const float* __restrict__ W1c,
                             const float* __restrict__ W2g, const float* __restrict__ W2c,
                             const float* __restrict__ Wd, u16* __restrict__ ws) {
  int j = blockIdx.x * 256 + threadIdx.x;
  if (j >= WTOT + nWdT) return;
  if (j >= WTOT) {
    const int jj = j - WTOT;           // jj = o*128 + c
    float* wdT = (float*)(ws + WTOT);
    const int o = jj >> 7, c = jj & 127;
    wdT[jj] = Wd[c * Fc + o];
    return;
  }
  const float* src; u16* dst; int K, N, jj;
  if (j < nW1g)                    { src = W1g; K = K1; N = 512; jj = j;                      dst = ws + oW1g; }
  else if (j < nW1g + nW1c)        { src = W1c; K = K1; N = 256; jj = j - nW1g;               dst = ws + oW1c; }
  else if (j < nW1g + nW1c + nW2g) { src = W2g; K = K2; N = 256; jj = j - nW1g - nW1c;        dst = ws + oW2g; }
  else                             { src = W2c; K = K2; N = 128; jj = j - nW1g - nW1c - nW2g; dst = ws + oW2c; }
  int n = jj / K, k = jj - n * K;
  dst[(size_t)n * K + k] = bf16_rne(src[(size_t)k * N + n]);
}

// Rolling-register weight pipe (unit = K-group of 32, 16B/lane fragment).
template <int NT, int D, int KT>
struct Pipe {
  const u16* wp[NT];
  bhalf8 bb[D][NT];
  __device__ __forceinline__ void init(const u16* __restrict__ W, const int* n0,
                                       int K, int lc, int ao) {
#pragma unroll
    for (int i = 0; i < NT; ++i) wp[i] = W + (size_t)(n0[i] + lc) * K + ao;
  }
  __device__ __forceinline__ void prefetch() {
#pragma unroll
    for (int d = 0; d < D; ++d)
#pragma unroll
      for (int i = 0; i < NT; ++i) bb[d][i] = *(const bhalf8*)(wp[i] + d * 32);
  }
  __device__ __forceinline__ void roll(int kt) {
    if (kt + D < KT) {
#pragma unroll
      for (int i = 0; i < NT; ++i) bb[kt % D][i] = *(const bhalf8*)(wp[i] + (kt + D) * 32);
    }
  }
};

template <int NT, int D, int KT, typename P, typename LD>
__device__ __forceinline__ void run_mm(P& p, fx4 (&acc)[NT], LD&& ld) {
#pragma unroll
  for (int kt = 0; kt < KT; ++kt) {
    bhalf8 ah, al;
    ld(kt, ah, al);
#pragma unroll
    for (int i = 0; i < NT; ++i) {
      acc[i] = __builtin_amdgcn_mfma_f32_16x16x32_bf16(ah, p.bb[kt % D][i], acc[i], 0, 0, 0);
      acc[i] = __builtin_amdgcn_mfma_f32_16x16x32_bf16(al, p.bb[kt % D][i], acc[i], 0, 0, 0);
    }
    p.roll(kt);
  }
}

__global__ __launch_bounds__(NTHR, 4)
void gru_mfma(const float* __restrict__ frames, const u16* __restrict__ ws,
              const float* __restrict__ b1g, const float* __restrict__ b1c,
              const float* __restrict__ b2g, const float* __restrict__ b2c,
              const float* __restrict__ bd, float* __restrict__ out) {
  extern __shared__ u16 sm[];

  const int tid = threadIdx.x;
  const int w = tid >> 6;          // wave 0..15
  const int l = tid & 63;
  const int lc = l & 15;           // col-in-tile / A row
  const int lk = l >> 4;
  const int ao = lk * 8;
  const int row0 = lk * 4;
  const int b0 = blockIdx.x * NB;
  const int w2 = w & 7;            // layer2 column group

  const float bR  = b1g[w * 16 + lc];
  const float bU  = b1g[256 + w * 16 + lc];
  const float bC1 = b1c[w * 16 + lc];
  const float bG2 = (w < 8) ? b2g[128 + w2 * 16 + lc] : b2g[w2 * 16 + lc];  // u2 : r2
  const float bC2 = b2c[w2 * 16 + lc];

  Pipe<2, 4, 9> pG1;  Pipe<1, 6, 9> pC1;  Pipe<1, 6, 12> pG2;  Pipe<1, 8, 12> pC2;
  const int n0g1[2] = {w * 16, 256 + w * 16};
  const int n0c1[1] = {w * 16};
  const int n0g2[1] = {(w < 8) ? (128 + w2 * 16) : (w2 * 16)};
  const int n0c2[1] = {w2 * 16};
  pG1.init(ws + oW1g, n0g1, K1, lc, ao);
  pC1.init(ws + oW1c, n0c1, K1, lc, ao);
  pG2.init(ws + oW2g, n0g2, K2, lc, ao);
  pC2.init(ws + oW2c, n0c2, K2, lc, ao);

  for (int i = tid; i < SM_TOT; i += NTHR) sm[i] = 0;

  // x staging: threads 0-511 stage one feature of one batch row
  const bool stager = tid < 512;
  const int xb = (tid >> 5) & 15, xf = tid & 31;
  const float* fptr = frames + (size_t)(b0 + xb) * (Tc * Fc) + xf;

  if (stager) {
    const float x0 = fptr[0];
    const u16 h = bf16_rne(x0);
    sm[oA1h + xb * LD1 + xf] = h;
    sm[oA1l + xb * LD1 + xf] = bf16_rne(x0 - bf16_f(h));
  }
  pG1.prefetch();
  LGKM_BARRIER();

  auto ldG1 = [&](int kt, bhalf8& ah, bhalf8& al) {        // A1 = [x | h1]
    const int idx = lc * LD1 + kt * 32 + ao;
    ah = *(const bhalf8*)&sm[oA1h + idx];
    al = *(const bhalf8*)&sm[oA1l + idx];
  };
  auto ldC1 = [&](int kt, bhalf8& ah, bhalf8& al) {        // [x | RH1]
    if (kt == 0) {
      const int idx = lc * LD1 + ao;
      ah = *(const bhalf8*)&sm[oA1h + idx];
      al = *(const bhalf8*)&sm[oA1l + idx];
    } else {
      const int idx = lc * LDR1 + (kt - 1) * 32 + ao;
      ah = *(const bhalf8*)&sm[oR1h + idx];
      al = *(const bhalf8*)&sm[oR1l + idx];
    }
  };
  auto ldG2 = [&](int kt, bhalf8& ah, bhalf8& al) {        // A2 = [h1n | h2]
    const int idx = lc * LD2 + kt * 32 + ao;
    ah = *(const bhalf8*)&sm[oA2h + idx];
    al = *(const bhalf8*)&sm[oA2l + idx];
  };
  auto ldC2 = [&](int kt, bhalf8& ah, bhalf8& al) {        // [h1n | RH2]
    if (kt < 8) {
      const int idx = lc * LD2 + kt * 32 + ao;
      ah = *(const bhalf8*)&sm[oA2h + idx];
      al = *(const bhalf8*)&sm[oA2l + idx];
    } else {
      const int idx = lc * LDR2 + (kt - 8) * 32 + ao;
      ah = *(const bhalf8*)&sm[oR2h + idx];
      al = *(const bhalf8*)&sm[oR2l + idx];
    }
  };

  for (int t = 0; t < Tc; ++t) {
    const float xn = (stager && t + 1 < Tc) ? fptr[(t + 1) * Fc] : 0.0f;

    // ==== G1: [x|h1] @ W1g -> r (tile0), u (tile1) ====
    fx4 acc[2] = { {bR, bR, bR, bR}, {bU, bU, bU, bU} };
    run_mm<2, 4, 9>(pG1, acc, ldG1);
    pC1.prefetch();

    float hold1[4], uu[4];
#pragma unroll
    for (int q = 0; q < 4; ++q) {
      const int row = row0 + q, col = w * 16 + lc;
      hold1[q] = bf16_f(sm[oA1h + row * LD1 + Fc + col]) +
                 bf16_f(sm[oA1l + row * LD1 + Fc + col]);
      uu[q] = sigm(acc[1][q]);
    }
#pragma unroll
    for (int q = 0; q < 4; ++q) {
      const int row = row0 + q, col = w * 16 + lc;
      const float rh = sigm(acc[0][q]) * hold1[q];
      const u16 hh = bf16_rne(rh);
      sm[oR1h + row * LDR1 + col] = hh;
      sm[oR1l + row * LDR1 + col] = bf16_rne(rh - bf16_f(hh));
    }
    LGKM_BARRIER();  // a: RH1 ready (G1 reads of A1 done)

    // ==== C1: [x|r*h1] @ W1c -> h1n ====
    fx4 accc[1] = { {bC1, bC1, bC1, bC1} };
    run_mm<1, 6, 9>(pC1, accc, ldC1);
    pG2.prefetch();

#pragma unroll
    for (int q = 0; q < 4; ++q) {
      const int row = row0 + q, col = w * 16 + lc;
      const float c = tanh_(accc[0][q]);
      const float hn = c + uu[q] * (hold1[q] - c);
      const u16 hh = bf16_rne(hn);
      const u16 hl = bf16_rne(hn - bf16_f(hh));
      sm[oA1h + row * LD1 + Fc + col] = hh;   // h1 state for t+1
      sm[oA1l + row * LD1 + Fc + col] = hl;
      sm[oA2h + row * LD2 + col] = hh;        // layer2 input
      sm[oA2l + row * LD2 + col] = hl;
    }
    LGKM_BARRIER();  // b: h1n ready (C1 reads of x/RH1 done)

    // ==== G2: [h1n|h2] @ W2g -> waves 0-7: u2; waves 8-15: r2 ====
    fx4 acc2[1] = { {bG2, bG2, bG2, bG2} };
    run_mm<1, 6, 12>(pG2, acc2, ldG2);
    if (w < 8) pC2.prefetch();

    float hold2[4], uu2[4];
#pragma unroll
    for (int q = 0; q < 4; ++q) {
      const int row = row0 + q, col = w2 * 16 + lc;
      hold2[q] = bf16_f(sm[oA2h + row * LD2 + U1 + col]) +
                 bf16_f(sm[oA2l + row * LD2 + U1 + col]);
      uu2[q] = sigm(acc2[0][q]);    // u2 (w<8) or r2 (w>=8)
    }
    if (w >= 8) {
#pragma unroll
      for (int q = 0; q < 4; ++q) {
        const int row = row0 + q, col = w2 * 16 + lc;
        const float rh = uu2[q] * hold2[q];
        const u16 hh = bf16_rne(rh);
        sm[oR2h + row * LDR2 + col] = hh;
        sm[oR2l + row * LDR2 + col] = bf16_rne(rh - bf16_f(hh));
      }
    }
    // stage x_{t+1} (C1 readers of A1x finished before barrier b)
    if (stager) {
      const u16 h = bf16_rne(xn);
      sm[oA1h + xb * LD1 + xf] = h;
      sm[oA1l + xb * LD1 + xf] = bf16_rne(xn - bf16_f(h));
    }
    LGKM_BARRIER();  // g: RH2 + x_{t+1} ready (G2 reads of A2 done)

    // ==== C2: [h1n|r2*h2] @ W2c -> h2n (waves 0-7) ====
    fx4 acc3[1] = { {bC2, bC2, bC2, bC2} };
    if (w < 8) {
      run_mm<1, 8, 12>(pC2, acc3, ldC2);
    }
    pG1.prefetch();            // next step's G1 weights in flight across d
    if (w < 8) {
#pragma unroll
      for (int q = 0; q < 4; ++q) {
        const int row = row0 + q, col = w2 * 16 + lc;
        const float c = tanh_(acc3[0][q]);
        const float hn = c + uu2[q] * (hold2[q] - c);
        const u16 hh = bf16_rne(hn);
        sm[oA2h + row * LD2 + U1 + col] = hh;       // h2 for t+1 (and final out)
        sm[oA2l + row * LD2 + U1 + col] = bf16_rne(hn - bf16_f(hh));
      }
    }
    LGKM_BARRIER();  // d: h2n ready
  }

  // ---- dense: out[b][o] = bd[o] + h2[b] . Wd[:,o]  (WdT fp32 in ws) ----
  if (tid < 512) {
    const float* wdT = (const float*)(ws + WTOT);   // [32][128]
    const int o = tid & 31, b = tid >> 5;
    const float4* wrow = (const float4*)(wdT + o * 128);
    float acc = bd[o];
#pragma unroll 8
    for (int c4 = 0; c4 < 32; ++c4) {
      const float4 wv = wrow[c4];
      const int c = c4 * 4;
      const int base = b * LD2 + U1 + c;
      const float h0 = bf16_f(sm[oA2h + base + 0]) + bf16_f(sm[oA2l + base + 0]);
      const float h1 = bf16_f(sm[oA2h + base + 1]) + bf16_f(sm[oA2l + base + 1]);
      const float h2 = bf16_f(sm[oA2h + base + 2]) + bf16_f(sm[oA2l + base + 2]);
      const float h3 = bf16_f(sm[oA2h + base + 3]) + bf16_f(sm[oA2l + base + 3]);
      acc = fmaf(h0, wv.x, fmaf(h1, wv.y, fmaf(h2, wv.z, fmaf(h3, wv.w, acc))));
    }
    out[(size_t)(b0 + b) * Fc + o] = acc;
  }
}

extern "C" void kernel_launch(void* const* d_in, const int* in_sizes, int n_in,
                              void* d_out, int out_size, void* d_ws, size_t ws_size,
                              hipStream_t stream) {
  const float* frames = (const float*)d_in[0];
  const float* W1g = (const float*)d_in[1];
  const float* b1g = (const float*)d_in[2];
  const float* W1c = (const float*)d_in[3];
  const float* b1c = (const float*)d_in[4];
  const float* W2g = (const float*)d_in[5];
  const float* b2g = (const float*)d_in[6];
  const float* W2c = (const float*)d_in[7];
  const float* b2c = (const float*)d_in[8];
  const float* Wd  = (const float*)d_in[9];
  const float* bd  = (const float*)d_in[10];
  u16* ws = (u16*)d_ws;
  float* outp = (float*)d_out;

  hipFuncSetAttribute(reinterpret_cast<const void*>(gru_mfma),
                      hipFuncAttributeMaxDynamicSharedMemorySize, (int)SMEM_BYTES);

  hipLaunchKernelGGL(prep_weights, dim3((WTOT + nWdT + 255) / 256), dim3(256), 0, stream,
                     W1g, W1c, W2g, W2c, Wd, ws);
  hipLaunchKernelGGL(gru_mfma, dim3(Bc / NB), dim3(NTHR), SMEM_BYTES, stream,
                     frames, ws, b1g, b1c, b2g, b2c, bd, outp);
}

// Round 12
// 1166.223 us; speedup vs baseline: 1.1898x; 1.1898x over previous
//
#include <hip/hip_runtime.h>

// 2-layer GRU (TF GRUCell) + dense via bf16 MFMA.
// R12 = R11 (16 waves / 1024 threads, NB=16, 4 barriers/step, RH buffers,
// LGKM-only barriers, cross-phase register prefetch) with the register
// budget PINNED: amdgpu_waves_per_eu(4,4) -> exactly 4 waves/SIMD, 128 VGPR
// cap == live-set size. R11 let the heuristic pick 64 VGPR (LDS-occupancy
// target) and spilled 2.3 GB. Pipe depths trimmed to fit: G1 D=3, C1 D=4,
// G2 D=4, C2 D=3 (~68 fragment regs + ~55 misc < 128).

typedef unsigned short u16;
typedef __attribute__((ext_vector_type(8))) short bhalf8;   // 8 bf16
typedef __attribute__((ext_vector_type(4))) float fx4;

constexpr int Bc = 4096, Tc = 64, Fc = 32, U1 = 256, U2 = 128;
constexpr int K1 = Fc + U1;   // 288
constexpr int K2 = U1 + U2;   // 384
constexpr int NB = 16, NTHR = 1024;
constexpr int LD1 = 296;      // A1 row stride (u16)
constexpr int LD2 = 392;      // A2 row stride
constexpr int LDR1 = 264;     // RH1 row stride
constexpr int LDR2 = 136;     // RH2 row stride

constexpr int nW1g = K1 * 512, nW1c = K1 * 256, nW2g = K2 * 256, nW2c = K2 * 128;
constexpr int oW1g = 0;
constexpr int oW1c = oW1g + nW1g;
constexpr int oW2g = oW1c + nW1c;
constexpr int oW2c = oW2g + nW2g;
constexpr int WTOT = oW2c + nW2c;   // 368640 u16
constexpr int nWdT = Fc * U2;       // 4096 floats

constexpr int oA1h = 0;
constexpr int oA1l = oA1h + 16 * LD1;
constexpr int oA2h = oA1l + 16 * LD1;
constexpr int oA2l = oA2h + 16 * LD2;
constexpr int oR1h = oA2l + 16 * LD2;
constexpr int oR1l = oR1h + 16 * LDR1;
constexpr int oR2h = oR1l + 16 * LDR1;
constexpr int oR2l = oR2h + 16 * LDR2;
constexpr int SM_TOT = oR2l + 16 * LDR2;          // 34816 u16
constexpr size_t SMEM_BYTES = (size_t)SM_TOT * 2; // 69632 B

#define LGKM_BARRIER() asm volatile("s_waitcnt lgkmcnt(0)\n\ts_barrier" ::: "memory")

__device__ __forceinline__ u16 bf16_rne(float x) {
  unsigned u = __float_as_uint(x);
  return (u16)((u + 0x7fffu + ((u >> 16) & 1u)) >> 16);
}
__device__ __forceinline__ float bf16_f(u16 h) {
  return __uint_as_float(((unsigned)h) << 16);
}
__device__ __forceinline__ float sigm(float x) { return 1.0f / (1.0f + __expf(-x)); }
__device__ __forceinline__ float tanh_(float x) {
  x = fminf(fmaxf(x, -15.0f), 15.0f);
  const float s = __expf(2.0f * x);
  return (s - 1.0f) / (s + 1.0f);
}

// ---- prep: W[K][N] fp32 -> WT[N][K] bf16; Wd[128][32] -> WdT fp32 ----
__global__ void prep_weights(const float* __restrict__ W1g, const float* __restrict__ W1c,
                             const float* __restrict__ W2g, const float* __restrict__ W2c,
                             const float* __restrict__ Wd, u16* __restrict__ ws) {
  int j = blockIdx.x * 256 + threadIdx.x;
  if (j >= WTOT + nWdT) return;
  if (j >= WTOT) {
    const int jj = j - WTOT;           // jj = o*128 + c
    float* wdT = (float*)(ws + WTOT);
    const int o = jj >> 7, c = jj & 127;
    wdT[jj] = Wd[c * Fc + o];
    return;
  }
  const float* src; u16* dst; int K, N, jj;
  if (j < nW1g)                    { src = W1g; K = K1; N = 512; jj = j;                      dst = ws + oW1g; }
  else if (j < nW1g + nW1c)        { src = W1c; K = K1; N = 256; jj = j - nW1g;               dst = ws + oW1c; }
  else if (j < nW1g + nW1c + nW2g) { src = W2g; K = K2; N = 256; jj = j - nW1g - nW1c;        dst = ws + oW2g; }
  else                             { src = W2c; K = K2; N = 128; jj = j - nW1g - nW1c - nW2g; dst = ws + oW2c; }
  int n = jj / K, k = jj - n * K;
  dst[(size_t)n * K + k] = bf16_rne(src[(size_t)k * N + n]);
}

// Rolling-register weight pipe (unit = K-group of 32, 16B/lane fragment).
template <int NT, int D, int KT>
struct Pipe {
  const u16* wp[NT];
  bhalf8 bb[D][NT];
  __device__ __forceinline__ void init(const u16* __restrict__ W, const int* n0,
                                       int K, int lc, int ao) {
#pragma unroll
    for (int i = 0; i < NT; ++i) wp[i] = W + (size_t)(n0[i] + lc) * K + ao;
  }
  __device__ __forceinline__ void prefetch() {
#pragma unroll
    for (int d = 0; d < D; ++d)
#pragma unroll
      for (int i = 0; i < NT; ++i) bb[d][i] = *(const bhalf8*)(wp[i] + d * 32);
  }
  __device__ __forceinline__ void roll(int kt) {
    if (kt + D < KT) {
#pragma unroll
      for (int i = 0; i < NT; ++i) bb[kt % D][i] = *(const bhalf8*)(wp[i] + (kt + D) * 32);
    }
  }
};

template <int NT, int D, int KT, typename P, typename LD>
__device__ __forceinline__ void run_mm(P& p, fx4 (&acc)[NT], LD&& ld) {
#pragma unroll
  for (int kt = 0; kt < KT; ++kt) {
    bhalf8 ah, al;
    ld(kt, ah, al);
#pragma unroll
    for (int i = 0; i < NT; ++i) {
      acc[i] = __builtin_amdgcn_mfma_f32_16x16x32_bf16(ah, p.bb[kt % D][i], acc[i], 0, 0, 0);
      acc[i] = __builtin_amdgcn_mfma_f32_16x16x32_bf16(al, p.bb[kt % D][i], acc[i], 0, 0, 0);
    }
    p.roll(kt);
  }
}

__global__ __attribute__((amdgpu_flat_work_group_size(NTHR, NTHR), amdgpu_waves_per_eu(4, 4)))
void gru_mfma(const float* __restrict__ frames, const u16* __restrict__ ws,
              const float* __restrict__ b1g, const float* __restrict__ b1c,
              const float* __restrict__ b2g, const float* __restrict__ b2c,
              const float* __restrict__ bd, float* __restrict__ out) {
  extern __shared__ u16 sm[];

  const int tid = threadIdx.x;
  const int w = tid >> 6;          // wave 0..15
  const int l = tid & 63;
  const int lc = l & 15;           // col-in-tile / A row
  const int lk = l >> 4;
  const int ao = lk * 8;
  const int row0 = lk * 4;
  const int b0 = blockIdx.x * NB;
  const int w2 = w & 7;            // layer2 column group

  const float bR  = b1g[w * 16 + lc];
  const float bU  = b1g[256 + w * 16 + lc];
  const float bC1 = b1c[w * 16 + lc];
  const float bG2 = (w < 8) ? b2g[128 + w2 * 16 + lc] : b2g[w2 * 16 + lc];  // u2 : r2
  const float bC2 = b2c[w2 * 16 + lc];

  Pipe<2, 3, 9> pG1;  Pipe<1, 4, 9> pC1;  Pipe<1, 4, 12> pG2;  Pipe<1, 3, 12> pC2;
  const int n0g1[2] = {w * 16, 256 + w * 16};
  const int n0c1[1] = {w * 16};
  const int n0g2[1] = {(w < 8) ? (128 + w2 * 16) : (w2 * 16)};
  const int n0c2[1] = {w2 * 16};
  pG1.init(ws + oW1g, n0g1, K1, lc, ao);
  pC1.init(ws + oW1c, n0c1, K1, lc, ao);
  pG2.init(ws + oW2g, n0g2, K2, lc, ao);
  pC2.init(ws + oW2c, n0c2, K2, lc, ao);

  for (int i = tid; i < SM_TOT; i += NTHR) sm[i] = 0;

  // x staging: threads 0-511 stage one feature of one batch row
  const bool stager = tid < 512;
  const int xb = (tid >> 5) & 15, xf = tid & 31;
  const float* fptr = frames + (size_t)(b0 + xb) * (Tc * Fc) + xf;

  if (stager) {
    const float x0 = fptr[0];
    const u16 h = bf16_rne(x0);
    sm[oA1h + xb * LD1 + xf] = h;
    sm[oA1l + xb * LD1 + xf] = bf16_rne(x0 - bf16_f(h));
  }
  pG1.prefetch();
  LGKM_BARRIER();

  auto ldG1 = [&](int kt, bhalf8& ah, bhalf8& al) {        // A1 = [x | h1]
    const int idx = lc * LD1 + kt * 32 + ao;
    ah = *(const bhalf8*)&sm[oA1h + idx];
    al = *(const bhalf8*)&sm[oA1l + idx];
  };
  auto ldC1 = [&](int kt, bhalf8& ah, bhalf8& al) {        // [x | RH1]
    if (kt == 0) {
      const int idx = lc * LD1 + ao;
      ah = *(const bhalf8*)&sm[oA1h + idx];
      al = *(const bhalf8*)&sm[oA1l + idx];
    } else {
      const int idx = lc * LDR1 + (kt - 1) * 32 + ao;
      ah = *(const bhalf8*)&sm[oR1h + idx];
      al = *(const bhalf8*)&sm[oR1l + idx];
    }
  };
  auto ldG2 = [&](int kt, bhalf8& ah, bhalf8& al) {        // A2 = [h1n | h2]
    const int idx = lc * LD2 + kt * 32 + ao;
    ah = *(const bhalf8*)&sm[oA2h + idx];
    al = *(const bhalf8*)&sm[oA2l + idx];
  };
  auto ldC2 = [&](int kt, bhalf8& ah, bhalf8& al) {        // [h1n | RH2]
    if (kt < 8) {
      const int idx = lc * LD2 + kt * 32 + ao;
      ah = *(const bhalf8*)&sm[oA2h + idx];
      al = *(const bhalf8*)&sm[oA2l + idx];
    } else {
      const int idx = lc * LDR2 + (kt - 8) * 32 + ao;
      ah = *(const bhalf8*)&sm[oR2h + idx];
      al = *(const bhalf8*)&sm[oR2l + idx];
    }
  };

  for (int t = 0; t < Tc; ++t) {
    const float xn = (stager && t + 1 < Tc) ? fptr[(t + 1) * Fc] : 0.0f;

    // ==== G1: [x|h1] @ W1g -> r (tile0), u (tile1) ====
    fx4 acc[2] = { {bR, bR, bR, bR}, {bU, bU, bU, bU} };
    run_mm<2, 3, 9>(pG1, acc, ldG1);
    pC1.prefetch();

    float hold1[4], uu[4];
#pragma unroll
    for (int q = 0; q < 4; ++q) {
      const int row = row0 + q, col = w * 16 + lc;
      hold1[q] = bf16_f(sm[oA1h + row * LD1 + Fc + col]) +
                 bf16_f(sm[oA1l + row * LD1 + Fc + col]);
      uu[q] = sigm(acc[1][q]);
    }
#pragma unroll
    for (int q = 0; q < 4; ++q) {
      const int row = row0 + q, col = w * 16 + lc;
      const float rh = sigm(acc[0][q]) * hold1[q];
      const u16 hh = bf16_rne(rh);
      sm[oR1h + row * LDR1 + col] = hh;
      sm[oR1l + row * LDR1 + col] = bf16_rne(rh - bf16_f(hh));
    }
    LGKM_BARRIER();  // a: RH1 ready (G1 reads of A1 done)

    // ==== C1: [x|r*h1] @ W1c -> h1n ====
    fx4 accc[1] = { {bC1, bC1, bC1, bC1} };
    run_mm<1, 4, 9>(pC1, accc, ldC1);
    pG2.prefetch();

#pragma unroll
    for (int q = 0; q < 4; ++q) {
      const int row = row0 + q, col = w * 16 + lc;
      const float c = tanh_(accc[0][q]);
      const float hn = c + uu[q] * (hold1[q] - c);
      const u16 hh = bf16_rne(hn);
      const u16 hl = bf16_rne(hn - bf16_f(hh));
      sm[oA1h + row * LD1 + Fc + col] = hh;   // h1 state for t+1
      sm[oA1l + row * LD1 + Fc + col] = hl;
      sm[oA2h + row * LD2 + col] = hh;        // layer2 input
      sm[oA2l + row * LD2 + col] = hl;
    }
    LGKM_BARRIER();  // b: h1n ready (C1 reads of x/RH1 done)

    // ==== G2: [h1n|h2] @ W2g -> waves 0-7: u2; waves 8-15: r2 ====
    fx4 acc2[1] = { {bG2, bG2, bG2, bG2} };
    run_mm<1, 4, 12>(pG2, acc2, ldG2);
    if (w < 8) pC2.prefetch();

    float hold2[4], uu2[4];
#pragma unroll
    for (int q = 0; q < 4; ++q) {
      const int row = row0 + q, col = w2 * 16 + lc;
      hold2[q] = bf16_f(sm[oA2h + row * LD2 + U1 + col]) +
                 bf16_f(sm[oA2l + row * LD2 + U1 + col]);
      uu2[q] = sigm(acc2[0][q]);    // u2 (w<8) or r2 (w>=8)
    }
    if (w >= 8) {
#pragma unroll
      for (int q = 0; q < 4; ++q) {
        const int row = row0 + q, col = w2 * 16 + lc;
        const float rh = uu2[q] * hold2[q];
        const u16 hh = bf16_rne(rh);
        sm[oR2h + row * LDR2 + col] = hh;
        sm[oR2l + row * LDR2 + col] = bf16_rne(rh - bf16_f(hh));
      }
    }
    // stage x_{t+1} (C1 readers of A1x finished before barrier b)
    if (stager) {
      const u16 h = bf16_rne(xn);
      sm[oA1h + xb * LD1 + xf] = h;
      sm[oA1l + xb * LD1 + xf] = bf16_rne(xn - bf16_f(h));
    }
    LGKM_BARRIER();  // g: RH2 + x_{t+1} ready (G2 reads of A2 done)

    // ==== C2: [h1n|r2*h2] @ W2c -> h2n (waves 0-7) ====
    fx4 acc3[1] = { {bC2, bC2, bC2, bC2} };
    if (w < 8) {
      run_mm<1, 3, 12>(pC2, acc3, ldC2);
    }
    pG1.prefetch();            // next step's G1 weights in flight across d
    if (w < 8) {
#pragma unroll
      for (int q = 0; q < 4; ++q) {
        const int row = row0 + q, col = w2 * 16 + lc;
        const float c = tanh_(acc3[0][q]);
        const float hn = c + uu2[q] * (hold2[q] - c);
        const u16 hh = bf16_rne(hn);
        sm[oA2h + row * LD2 + U1 + col] = hh;       // h2 for t+1 (and final out)
        sm[oA2l + row * LD2 + U1 + col] = bf16_rne(hn - bf16_f(hh));
      }
    }
    LGKM_BARRIER();  // d: h2n ready
  }

  // ---- dense: out[b][o] = bd[o] + h2[b] . Wd[:,o]  (WdT fp32 in ws) ----
  if (tid < 512) {
    const float* wdT = (const float*)(ws + WTOT);   // [32][128]
    const int o = tid & 31, b = tid >> 5;
    const float4* wrow = (const float4*)(wdT + o * 128);
    float acc = bd[o];
#pragma unroll 8
    for (int c4 = 0; c4 < 32; ++c4) {
      const float4 wv = wrow[c4];
      const int c = c4 * 4;
      const int base = b * LD2 + U1 + c;
      const float h0 = bf16_f(sm[oA2h + base + 0]) + bf16_f(sm[oA2l + base + 0]);
      const float h1 = bf16_f(sm[oA2h + base + 1]) + bf16_f(sm[oA2l + base + 1]);
      const float h2 = bf16_f(sm[oA2h + base + 2]) + bf16_f(sm[oA2l + base + 2]);
      const float h3 = bf16_f(sm[oA2h + base + 3]) + bf16_f(sm[oA2l + base + 3]);
      acc = fmaf(h0, wv.x, fmaf(h1, wv.y, fmaf(h2, wv.z, fmaf(h3, wv.w, acc))));
    }
    out[(size_t)(b0 + b) * Fc + o] = acc;
  }
}

extern "C" void kernel_launch(void* const* d_in, const int* in_sizes, int n_in,
                              void* d_out, int out_size, void* d_ws, size_t ws_size,
                              hipStream_t stream) {
  const float* frames = (const float*)d_in[0];
  const float* W1g = (const float*)d_in[1];
  const float* b1g = (const float*)d_in[2];
  const float* W1c = (const float*)d_in[3];
  const float* b1c = (const float*)d_in[4];
  const float* W2g = (const float*)d_in[5];
  const float* b2g = (const float*)d_in[6];
  const float* W2c = (const float*)d_in[7];
  const float* b2c = (const float*)d_in[8];
  const float* Wd  = (const float*)d_in[9];
  const float* bd  = (const float*)d_in[10];
  u16* ws = (u16*)d_ws;
  float* outp = (float*)d_out;

  hipFuncSetAttribute(reinterpret_cast<const void*>(gru_mfma),
                      hipFuncAttributeMaxDynamicSharedMemorySize, (int)SMEM_BYTES);

  hipLaunchKernelGGL(prep_weights, dim3((WTOT + nWdT + 255) / 256), dim3(256), 0, stream,
                     W1g, W1c, W2g, W2c, Wd, ws);
  hipLaunchKernelGGL(gru_mfma, dim3(Bc / NB), dim3(NTHR), SMEM_BYTES, stream,
                     frames, ws, b1g, b1c, b2g, b2c, bd, outp);
}

// Round 13
// 979.786 us; speedup vs baseline: 1.4162x; 1.1903x over previous
//
#include <hip/hip_runtime.h>

// 2-layer GRU (TF GRUCell) + dense via bf16 MFMA.
// R13: cross-timestep layer pipelining. Super-step s runs layer1(t=s) and
// layer2(t=s-1) CONCURRENTLY (they both depend only on h1n(s-1)):
//   phase A: G1(s) || G2(s-1)   -> barrier
//   phase B: C1(s) || C2(s-1)   -> barrier      (2 barriers/step vs R5's 9)
// Every wave runs both layers' matmuls (two independent weight streams in
// flight -> 2x MLP). Ping-pong x and h1 panels + separate RH buffers remove
// all WAR hazards. r*h stored as SINGLE bf16 (saves MFMAs + LDS; adds ~2^-9
// relative error on candidate path only). 512 thr / static 59KB LDS keeps
// the proven 128-VGPR no-spill compile shape (R6-R12 lesson).

typedef unsigned short u16;
typedef __attribute__((ext_vector_type(8))) short bhalf8;   // 8 bf16
typedef __attribute__((ext_vector_type(4))) float fx4;

constexpr int Bc = 4096, Tc = 64, Fc = 32, U1 = 256, U2 = 128;
constexpr int K1 = Fc + U1;   // 288
constexpr int K2 = U1 + U2;   // 384
constexpr int NB = 16, NTHR = 512;
constexpr int LDX = 40;       // x row stride (u16)
constexpr int LDH = 264;      // h1 / RH1 row stride
constexpr int LDH2 = 136;     // h2 / RH2 row stride

// d_ws: u16 transposed bf16 weights, then fp32 WdT[32][128].
constexpr int nW1g = K1 * 512, nW1c = K1 * 256, nW2g = K2 * 256, nW2c = K2 * 128;
constexpr int oW1g = 0;
constexpr int oW1c = oW1g + nW1g;
constexpr int oW2g = oW1c + nW1c;
constexpr int oW2c = oW2g + nW2g;
constexpr int WTOT = oW2c + nW2c;   // 368640 u16
constexpr int nWdT = Fc * U2;

// LDS (u16 offsets). x ping: [2][hi/lo][16*LDX]; h1 ping: [2][hi/lo][16*LDH];
// h2: [hi/lo][16*LDH2]; RH1 single: [16*LDH]; RH2 single: [16*LDH2].
constexpr int oXp  = 0;
constexpr int oH1  = oXp + 4 * 16 * LDX;     // 2560
constexpr int oH2  = oH1 + 4 * 16 * LDH;     // 19456
constexpr int oRH1 = oH2 + 2 * 16 * LDH2;    // 23808
constexpr int oRH2 = oRH1 + 16 * LDH;        // 28032
constexpr int SM_TOT = oRH2 + 16 * LDH2;     // 30208 u16 = 60416 B

#define LGKM_BARRIER() asm volatile("s_waitcnt lgkmcnt(0)\n\ts_barrier" ::: "memory")

__device__ __forceinline__ u16 bf16_rne(float x) {
  unsigned u = __float_as_uint(x);
  return (u16)((u + 0x7fffu + ((u >> 16) & 1u)) >> 16);
}
__device__ __forceinline__ float bf16_f(u16 h) {
  return __uint_as_float(((unsigned)h) << 16);
}
__device__ __forceinline__ float sigm(float x) { return 1.0f / (1.0f + __expf(-x)); }
__device__ __forceinline__ float tanh_(float x) {
  x = fminf(fmaxf(x, -15.0f), 15.0f);
  const float s = __expf(2.0f * x);
  return (s - 1.0f) / (s + 1.0f);
}

// ---- prep: W[K][N] fp32 -> WT[N][K] bf16; Wd[128][32] -> WdT fp32 ----
__global__ void prep_weights(const float* __restrict__ W1g, const float* __restrict__ W1c,
                             const float* __restrict__ W2g, const float* __restrict__ W2c,
                             const float* __restrict__ Wd, u16* __restrict__ ws) {
  int j = blockIdx.x * 256 + threadIdx.x;
  if (j >= WTOT + nWdT) return;
  if (j >= WTOT) {
    const int jj = j - WTOT;
    float* wdT = (float*)(ws + WTOT);
    const int o = jj >> 7, c = jj & 127;
    wdT[jj] = Wd[c * Fc + o];
    return;
  }
  const float* src; u16* dst; int K, N, jj;
  if (j < nW1g)                    { src = W1g; K = K1; N = 512; jj = j;                      dst = ws + oW1g; }
  else if (j < nW1g + nW1c)        { src = W1c; K = K1; N = 256; jj = j - nW1g;               dst = ws + oW1c; }
  else if (j < nW1g + nW1c + nW2g) { src = W2g; K = K2; N = 256; jj = j - nW1g - nW1c;        dst = ws + oW2g; }
  else                             { src = W2c; K = K2; N = 128; jj = j - nW1g - nW1c - nW2g; dst = ws + oW2c; }
  int n = jj / K, k = jj - n * K;
  dst[(size_t)n * K + k] = bf16_rne(src[(size_t)k * N + n]);
}

// Rolling-register weight pipe (unit = K-group of 32, 16B/lane fragment).
template <int NT, int D, int KT>
struct Pipe {
  const u16* wp[NT];
  bhalf8 bb[D][NT];
  __device__ __forceinline__ void init(const u16* __restrict__ W, const int* n0,
                                       int K, int lc, int ao) {
#pragma unroll
    for (int i = 0; i < NT; ++i) wp[i] = W + (size_t)(n0[i] + lc) * K + ao;
  }
  __device__ __forceinline__ void prefetch() {
#pragma unroll
    for (int d = 0; d < D; ++d)
#pragma unroll
      for (int i = 0; i < NT; ++i) bb[d][i] = *(const bhalf8*)(wp[i] + d * 32);
  }
  __device__ __forceinline__ void roll(int kt) {
    if (kt + D < KT) {
#pragma unroll
      for (int i = 0; i < NT; ++i) bb[kt % D][i] = *(const bhalf8*)(wp[i] + (kt + D) * 32);
    }
  }
};

__global__ __launch_bounds__(NTHR, 2)
void gru_mfma(const float* __restrict__ frames, const u16* __restrict__ ws,
              const float* __restrict__ b1g, const float* __restrict__ b1c,
              const float* __restrict__ b2g, const float* __restrict__ b2c,
              const float* __restrict__ bd, float* __restrict__ out) {
  __shared__ alignas(16) u16 sm[SM_TOT];

  const int tid = threadIdx.x;
  const int w = tid >> 6;          // wave 0..7
  const int l = tid & 63;
  const int lc = l & 15;           // A row / col-in-tile
  const int lk = l >> 4;
  const int ao = lk * 8;
  const int row0 = lk * 4;
  const int b0 = blockIdx.x * NB;

  // layer1: wave owns r/u/c cols {32w..32w+31}; layer2: cols {16w..16w+15}
  const float bR0 = b1g[w * 32 + lc],       bR1 = b1g[w * 32 + 16 + lc];
  const float bU0 = b1g[256 + w * 32 + lc], bU1 = b1g[256 + w * 32 + 16 + lc];
  const float bC10 = b1c[w * 32 + lc],      bC11 = b1c[w * 32 + 16 + lc];
  const float bR2 = b2g[w * 16 + lc];       // r2
  const float bU2 = b2g[128 + w * 16 + lc]; // u2
  const float bC2 = b2c[w * 16 + lc];

  Pipe<4, 3, 9> pG1;  Pipe<2, 3, 12> pG2;  Pipe<2, 3, 9> pC1;  Pipe<1, 3, 12> pC2;
  const int n0g1[4] = {w * 32, w * 32 + 16, 256 + w * 32, 256 + w * 32 + 16};
  const int n0g2[2] = {w * 16, 128 + w * 16};
  const int n0c1[2] = {w * 32, w * 32 + 16};
  const int n0c2[1] = {w * 16};
  pG1.init(ws + oW1g, n0g1, K1, lc, ao);
  pG2.init(ws + oW2g, n0g2, K2, lc, ao);
  pC1.init(ws + oW1c, n0c1, K1, lc, ao);
  pC2.init(ws + oW2c, n0c2, K2, lc, ao);

  for (int i = tid; i < SM_TOT; i += NTHR) sm[i] = 0;

  const int xb = tid >> 5, xf = tid & 31;
  const float* fptr = frames + (size_t)(b0 + xb) * (Tc * Fc) + xf;

  // prologue: stage x_0 into ping 0; prefetch both phase-A pipes
  {
    const float x0 = fptr[0];
    const u16 h = bf16_rne(x0);
    sm[oXp + xb * LDX + xf] = h;
    sm[oXp + 16 * LDX + xb * LDX + xf] = bf16_rne(x0 - bf16_f(h));
  }
  pG1.prefetch();
  pG2.prefetch();
  LGKM_BARRIER();

  for (int s = 0; s <= Tc; ++s) {
    const int cur = s & 1, prv = cur ^ 1;
    const bool doL1 = (s < Tc), doL2 = (s > 0);
    const int xpc = oXp + cur * (2 * 16 * LDX);          // x[s] hi base
    const int h1p = oH1 + prv * (2 * 16 * LDH);          // h1n(s-1) hi base
    const int h1c = oH1 + cur * (2 * 16 * LDH);          // h1n(s) hi base
    const float xn = (doL1 && s + 1 < Tc) ? fptr[(s + 1) * Fc] : 0.0f;

    // ================= phase A: G1(s) || G2(s-1) =================
    fx4 aG[4] = { {bR0, bR0, bR0, bR0}, {bR1, bR1, bR1, bR1},
                  {bU0, bU0, bU0, bU0}, {bU1, bU1, bU1, bU1} };
    if (doL1) {
#pragma unroll
      for (int kt = 0; kt < 9; ++kt) {
        bhalf8 ah, al;
        if (kt == 0) {
          const int idx = lc * LDX + ao;
          ah = *(const bhalf8*)&sm[xpc + idx];
          al = *(const bhalf8*)&sm[xpc + 16 * LDX + idx];
        } else {
          const int idx = lc * LDH + (kt - 1) * 32 + ao;
          ah = *(const bhalf8*)&sm[h1p + idx];
          al = *(const bhalf8*)&sm[h1p + 16 * LDH + idx];
        }
#pragma unroll
        for (int i = 0; i < 4; ++i) {
          aG[i] = __builtin_amdgcn_mfma_f32_16x16x32_bf16(ah, pG1.bb[kt % 3][i], aG[i], 0, 0, 0);
          aG[i] = __builtin_amdgcn_mfma_f32_16x16x32_bf16(al, pG1.bb[kt % 3][i], aG[i], 0, 0, 0);
        }
        pG1.roll(kt);
      }
    }
    fx4 a2[2] = { {bR2, bR2, bR2, bR2}, {bU2, bU2, bU2, bU2} };
    if (doL2) {
#pragma unroll
      for (int kt = 0; kt < 12; ++kt) {
        bhalf8 ah, al;
        if (kt < 8) {
          const int idx = lc * LDH + kt * 32 + ao;
          ah = *(const bhalf8*)&sm[h1p + idx];
          al = *(const bhalf8*)&sm[h1p + 16 * LDH + idx];
        } else {
          const int idx = lc * LDH2 + (kt - 8) * 32 + ao;
          ah = *(const bhalf8*)&sm[oH2 + idx];
          al = *(const bhalf8*)&sm[oH2 + 16 * LDH2 + idx];
        }
#pragma unroll
        for (int i = 0; i < 2; ++i) {
          a2[i] = __builtin_amdgcn_mfma_f32_16x16x32_bf16(ah, pG2.bb[kt % 3][i], a2[i], 0, 0, 0);
          a2[i] = __builtin_amdgcn_mfma_f32_16x16x32_bf16(al, pG2.bb[kt % 3][i], a2[i], 0, 0, 0);
        }
        pG2.roll(kt);
      }
    }
    pC1.prefetch();
    pC2.prefetch();

    float hold1[2][4], uu1[2][4];
    if (doL1) {
#pragma unroll
      for (int i = 0; i < 2; ++i)
#pragma unroll
        for (int q = 0; q < 4; ++q) {
          const int row = row0 + q, col = w * 32 + i * 16 + lc;
          hold1[i][q] = bf16_f(sm[h1p + row * LDH + col]) +
                        bf16_f(sm[h1p + 16 * LDH + row * LDH + col]);
          uu1[i][q] = sigm(aG[2 + i][q]);
          sm[oRH1 + row * LDH + col] = bf16_rne(sigm(aG[i][q]) * hold1[i][q]);
        }
    }
    float hold2[4], uu2[4];
    if (doL2) {
#pragma unroll
      for (int q = 0; q < 4; ++q) {
        const int row = row0 + q, col = w * 16 + lc;
        hold2[q] = bf16_f(sm[oH2 + row * LDH2 + col]) +
                   bf16_f(sm[oH2 + 16 * LDH2 + row * LDH2 + col]);
        uu2[q] = sigm(a2[1][q]);
        sm[oRH2 + row * LDH2 + col] = bf16_rne(sigm(a2[0][q]) * hold2[q]);
      }
    }
    LGKM_BARRIER();  // A: RH1, RH2 ready

    // ================= phase B: C1(s) || C2(s-1) =================
    fx4 aC1[2] = { {bC10, bC10, bC10, bC10}, {bC11, bC11, bC11, bC11} };
    if (doL1) {
#pragma unroll
      for (int kt = 0; kt < 9; ++kt) {
        if (kt == 0) {
          const int idx = lc * LDX + ao;
          const bhalf8 ah = *(const bhalf8*)&sm[xpc + idx];
          const bhalf8 al = *(const bhalf8*)&sm[xpc + 16 * LDX + idx];
#pragma unroll
          for (int i = 0; i < 2; ++i) {
            aC1[i] = __builtin_amdgcn_mfma_f32_16x16x32_bf16(ah, pC1.bb[0][i], aC1[i], 0, 0, 0);
            aC1[i] = __builtin_amdgcn_mfma_f32_16x16x32_bf16(al, pC1.bb[0][i], aC1[i], 0, 0, 0);
          }
        } else {
          const int idx = lc * LDH + (kt - 1) * 32 + ao;
          const bhalf8 as = *(const bhalf8*)&sm[oRH1 + idx];
#pragma unroll
          for (int i = 0; i < 2; ++i)
            aC1[i] = __builtin_amdgcn_mfma_f32_16x16x32_bf16(as, pC1.bb[kt % 3][i], aC1[i], 0, 0, 0);
        }
        pC1.roll(kt);
      }
    }
    fx4 aC2 = {bC2, bC2, bC2, bC2};
    if (doL2) {
#pragma unroll
      for (int kt = 0; kt < 12; ++kt) {
        if (kt < 8) {
          const int idx = lc * LDH + kt * 32 + ao;
          const bhalf8 ah = *(const bhalf8*)&sm[h1p + idx];
          const bhalf8 al = *(const bhalf8*)&sm[h1p + 16 * LDH + idx];
          aC2 = __builtin_amdgcn_mfma_f32_16x16x32_bf16(ah, pC2.bb[kt % 3][0], aC2, 0, 0, 0);
          aC2 = __builtin_amdgcn_mfma_f32_16x16x32_bf16(al, pC2.bb[kt % 3][0], aC2, 0, 0, 0);
        } else {
          const int idx = lc * LDH2 + (kt - 8) * 32 + ao;
          const bhalf8 as = *(const bhalf8*)&sm[oRH2 + idx];
          aC2 = __builtin_amdgcn_mfma_f32_16x16x32_bf16(as, pC2.bb[kt % 3][0], aC2, 0, 0, 0);
        }
        pC2.roll(kt);
      }
    }
    pG1.prefetch();
    pG2.prefetch();

    if (doL1) {
#pragma unroll
      for (int i = 0; i < 2; ++i)
#pragma unroll
        for (int q = 0; q < 4; ++q) {
          const int row = row0 + q, col = w * 32 + i * 16 + lc;
          const float c = tanh_(aC1[i][q]);
          const float hn = c + uu1[i][q] * (hold1[i][q] - c);
          const u16 hh = bf16_rne(hn);
          sm[h1c + row * LDH + col] = hh;
          sm[h1c + 16 * LDH + row * LDH + col] = bf16_rne(hn - bf16_f(hh));
        }
    }
    if (doL2) {
#pragma unroll
      for (int q = 0; q < 4; ++q) {
        const int row = row0 + q, col = w * 16 + lc;
        const float c = tanh_(aC2[q]);
        const float hn = c + uu2[q] * (hold2[q] - c);
        const u16 hh = bf16_rne(hn);
        sm[oH2 + row * LDH2 + col] = hh;
        sm[oH2 + 16 * LDH2 + row * LDH2 + col] = bf16_rne(hn - bf16_f(hh));
      }
    }
    if (doL1 && s + 1 < Tc) {   // stage x_{s+1} into the other ping
      const int xpn = oXp + ((s + 1) & 1) * (2 * 16 * LDX);
      const u16 h = bf16_rne(xn);
      sm[xpn + xb * LDX + xf] = h;
      sm[xpn + 16 * LDX + xb * LDX + xf] = bf16_rne(xn - bf16_f(h));
    }
    LGKM_BARRIER();  // B: h1n(s), h2n(s-1), x_{s+1} ready
  }

  // ---- dense: out[b][o] = bd[o] + h2[b] . Wd[:,o]  (WdT fp32 in ws) ----
  {
    const float* wdT = (const float*)(ws + WTOT);   // [32][128]
    const int o = tid & 31, b = tid >> 5;
    const float4* wrow = (const float4*)(wdT + o * 128);
    float acc = bd[o];
#pragma unroll 8
    for (int c4 = 0; c4 < 32; ++c4) {
      const float4 wv = wrow[c4];
      const int c = c4 * 4;
      const int base = b * LDH2 + c;
      const float h0 = bf16_f(sm[oH2 + base + 0]) + bf16_f(sm[oH2 + 16 * LDH2 + base + 0]);
      const float h1 = bf16_f(sm[oH2 + base + 1]) + bf16_f(sm[oH2 + 16 * LDH2 + base + 1]);
      const float h2 = bf16_f(sm[oH2 + base + 2]) + bf16_f(sm[oH2 + 16 * LDH2 + base + 2]);
      const float h3 = bf16_f(sm[oH2 + base + 3]) + bf16_f(sm[oH2 + 16 * LDH2 + base + 3]);
      acc = fmaf(h0, wv.x, fmaf(h1, wv.y, fmaf(h2, wv.z, fmaf(h3, wv.w, acc))));
    }
    out[(size_t)(b0 + b) * Fc + o] = acc;
  }
}

extern "C" void kernel_launch(void* const* d_in, const int* in_sizes, int n_in,
                              void* d_out, int out_size, void* d_ws, size_t ws_size,
                              hipStream_t stream) {
  const float* frames = (const float*)d_in[0];
  const float* W1g = (const float*)d_in[1];
  const float* b1g = (const float*)d_in[2];
  const float* W1c = (const float*)d_in[3];
  const float* b1c = (const float*)d_in[4];
  const float* W2g = (const float*)d_in[5];
  const float* b2g = (const float*)d_in[6];
  const float* W2c = (const float*)d_in[7];
  const float* b2c = (const float*)d_in[8];
  const float* Wd  = (const float*)d_in[9];
  const float* bd  = (const float*)d_in[10];
  u16* ws = (u16*)d_ws;
  float* outp = (float*)d_out;

  hipLaunchKernelGGL(prep_weights, dim3((WTOT + nWdT + 255) / 256), dim3(256), 0, stream,
                     W1g, W1c, W2g, W2c, Wd, ws);
  hipLaunchKernelGGL(gru_mfma, dim3(Bc / NB), dim3(NTHR), 0, stream,
                     frames, ws, b1g, b1c, b2g, b2c, bd, outp);
}